// Round 3
// baseline (374.276 us; speedup 1.0000x reference)
//
#include <hip/hip_runtime.h>
#include <math.h>

#define B_   24
#define NA_  50
#define T_   10
#define NV_  196
#define D_   512
#define M_   1200          // B*NA audio rows
#define MPAD 1280          // padded to 10 tiles of 128
#define NVP  224           // 196 padded to 14*16
#define YT_  240           // B*T
#define VROWS (YT_ * NVP)  // 53760 padded visual rows
#define CHB  22528         // bytes per double-buffer half: A 8192 + V 14336

typedef __bf16 bf16x8 __attribute__((ext_vector_type(8)));
typedef float  f32x4  __attribute__((ext_vector_type(4)));
typedef unsigned short ushort8 __attribute__((ext_vector_type(8)));

__device__ __forceinline__ unsigned short f2bf(float f) {
    unsigned u = __float_as_uint(f);
    u += 0x7FFF + ((u >> 16) & 1);       // RNE
    return (unsigned short)(u >> 16);
}

__device__ __forceinline__ void gload16(const void* g, void* l) {
    __builtin_amdgcn_global_load_lds(
        (const __attribute__((address_space(1))) unsigned int*)g,
        (__attribute__((address_space(3))) unsigned int*)l, 16, 0, 0);
}

// ---- merged: L2-normalize + bf16 convert for V and A; also zero-inits accs ----
// grid: (VROWS + MPAD)/4 = 13760 blocks x 256. One wave per row.
__global__ void normconv_kernel(const float* __restrict__ vf, const float* __restrict__ af,
                                const float* __restrict__ tempPtr,
                                unsigned short* __restrict__ Vbf, unsigned short* __restrict__ Abf,
                                float* __restrict__ accs) {
    if (blockIdx.x == 0 && threadIdx.x < 3) accs[threadIdx.x] = 0.0f;
    int w = threadIdx.x >> 6, lane = threadIdx.x & 63;
    int row = blockIdx.x * 4 + w;
    const float* p = nullptr;
    unsigned short* dstp;
    float tscale = 1.0f;
    if (row < VROWS) {
        int yt = row / NVP, vv = row - yt * NVP;
        dstp = Vbf + (size_t)row * D_;
        if (vv < NV_) p = vf + ((size_t)yt * NV_ + vv) * D_;
    } else {
        int ar = row - VROWS;
        if (ar >= MPAD) return;
        dstp = Abf + (size_t)ar * D_;
        if (ar < M_) { p = af + (size_t)ar * D_; tscale = tempPtr[0]; }
    }
    ushort8* dst = (ushort8*)(dstp + lane * 8);
    if (p) {
        float4 u = *(const float4*)(p + lane * 8);
        float4 v = *(const float4*)(p + lane * 8 + 4);
        float s = u.x*u.x + u.y*u.y + u.z*u.z + u.w*u.w
                + v.x*v.x + v.y*v.y + v.z*v.z + v.w*v.w;
        #pragma unroll
        for (int off = 32; off; off >>= 1) s += __shfl_xor(s, off, 64);
        float sc = 1.0f / (fmaxf(sqrtf(s), 1e-12f) * tscale);
        ushort8 o;
        o[0]=f2bf(u.x*sc); o[1]=f2bf(u.y*sc); o[2]=f2bf(u.z*sc); o[3]=f2bf(u.w*sc);
        o[4]=f2bf(v.x*sc); o[5]=f2bf(v.y*sc); o[6]=f2bf(v.z*sc); o[7]=f2bf(v.w*sc);
        *dst = o;
    } else {
        ushort8 z = (ushort8)0;
        *dst = z;
    }
}

// ---- MFMA GEMM + fused max/clip reductions, double-buffered, XCD-swizzled ----
// grid: (10, 240) -> remapped so each XCD owns 30 yt groups with row-tiles adjacent.
// block: 256 (4 waves, 2x2). Block tile: 128 rows x 224 cols, K=512, BK=32.
// LDS layout per buffer: 22 units of 1024B; unit u = 16 rows x 32 bf16, stored
// k-major: (k-chunk c)*256 + (row r)*16  -> fragment reads are 2-way-bank only.
__global__ __launch_bounds__(256) void simred_kernel(
    const unsigned short* __restrict__ Abf, const unsigned short* __restrict__ Vbf,
    float* __restrict__ maxvis, float* __restrict__ accNonneg)
{
    __shared__ __align__(16) unsigned char lds[2 * CHB];
    __shared__ float maxred[2][128];
    __shared__ float redbuf[4];

    const int tid  = threadIdx.x;
    const int lane = tid & 63;
    const int w    = tid >> 6;
    const int q    = lane >> 4;    // k-chunk (staging) / frag quad
    const int m16  = lane & 15;    // row (staging) / frag row-col index
    const int wr   = w & 1;        // wave row half (64 rows)
    const int wc   = w >> 1;       // wave col half (112 cols)

    // XCD-aware swizzle: flat%8 = XCD (dispatch heuristic). Each XCD: 30 yts x 10 row-tiles.
    const int flat = blockIdx.x + gridDim.x * blockIdx.y;   // 0..2399
    const int xcd  = flat & 7;
    const int slot = flat >> 3;          // 0..299
    const int grp  = slot / 10;          // 0..29
    const int rt   = slot - grp * 10;    // 0..9 row tile (innermost: V-tile reuse)
    const int yt   = xcd * 30 + grp;
    const int rowA0 = rt * 128;
    const size_t vRow0 = (size_t)yt * NVP;

    // staging units: 0..7 = A row blocks, 8..21 = V row blocks; lane -> (row m16, chunk q)
    const unsigned short* gp[6];
    int lpOff[6];
    int nun = 0;
    #pragma unroll
    for (int i = 0; i < 6; ++i) {
        int u = w + 4 * i;
        if (u < 22) {
            if (u < 8) gp[nun] = Abf + (size_t)(rowA0 + u * 16 + m16) * D_ + q * 8;
            else       gp[nun] = Vbf + (vRow0 + (size_t)((u - 8) * 16 + m16)) * D_ + q * 8;
            lpOff[nun] = u * 1024;
            ++nun;
        }
    }

    // fragment offsets within a buffer (k-major units)
    int aOff[4], bOff[7];
    #pragma unroll
    for (int i = 0; i < 4; ++i) aOff[i] = (wr * 4 + i) * 1024 + q * 256 + m16 * 16;
    #pragma unroll
    for (int j = 0; j < 7; ++j) bOff[j] = 8192 + (wc * 7 + j) * 1024 + q * 256 + m16 * 16;

    f32x4 acc[4][7];
    #pragma unroll
    for (int i = 0; i < 4; ++i)
        #pragma unroll
        for (int j = 0; j < 7; ++j) acc[i][j] = (f32x4)0.0f;

    // prologue: chunk 0 -> buffer 0
    #pragma unroll
    for (int i = 0; i < 6; ++i)
        if (i < nun) gload16(gp[i], lds + lpOff[i]);
    __syncthreads();

    int cur = 0;
    for (int c = 0; c < 16; ++c) {
        // prefetch chunk c+1 into the other buffer (drained by this iter's barrier,
        // overlapped with frag reads + MFMA below)
        if (c < 15) {
            const int nb = cur ^ 1;
            #pragma unroll
            for (int i = 0; i < 6; ++i)
                if (i < nun) gload16(gp[i] + (c + 1) * 32, lds + nb * CHB + lpOff[i]);
        }
        const unsigned char* base = lds + cur * CHB;
        bf16x8 afr[4], bfr[7];
        #pragma unroll
        for (int i = 0; i < 4; ++i) afr[i] = *(const bf16x8*)(base + aOff[i]);
        #pragma unroll
        for (int j = 0; j < 7; ++j) bfr[j] = *(const bf16x8*)(base + bOff[j]);
        #pragma unroll
        for (int i = 0; i < 4; ++i)
            #pragma unroll
            for (int j = 0; j < 7; ++j)
                acc[i][j] = __builtin_amdgcn_mfma_f32_16x16x32_bf16(afr[i], bfr[j], acc[i][j], 0, 0, 0);
        __syncthreads();
        cur ^= 1;
    }

    // ---- clip(s,-20,0)^2 partial sum (zero-padded rows/cols contribute exactly 0) ----
    float cs = 0.0f;
    #pragma unroll
    for (int i = 0; i < 4; ++i)
        #pragma unroll
        for (int j = 0; j < 7; ++j)
            #pragma unroll
            for (int r = 0; r < 4; ++r) {
                float v = acc[i][j][r];
                float cv = fminf(fmaxf(v, -20.0f), 0.0f);
                cs += cv * cv;
            }
    #pragma unroll
    for (int off = 32; off; off >>= 1) cs += __shfl_xor(cs, off, 64);
    if (lane == 0) redbuf[w] = cs;

    // ---- per-row max over valid cols (C/D: col=lane&15, row=q*4+reg) ----
    bool colv[7];
    #pragma unroll
    for (int j = 0; j < 7; ++j) colv[j] = (wc * 112 + j * 16 + m16) < NV_;
    #pragma unroll
    for (int i = 0; i < 4; ++i) {
        float mx[4] = {-3e38f, -3e38f, -3e38f, -3e38f};
        #pragma unroll
        for (int j = 0; j < 7; ++j)
            #pragma unroll
            for (int r = 0; r < 4; ++r)
                mx[r] = fmaxf(mx[r], colv[j] ? acc[i][j][r] : -3e38f);
        #pragma unroll
        for (int r = 0; r < 4; ++r) {
            float mm = mx[r];
            #pragma unroll
            for (int off = 1; off <= 8; off <<= 1) mm = fmaxf(mm, __shfl_xor(mm, off, 64));
            if (m16 == 0) maxred[wc][wr * 64 + i * 16 + q * 4 + r] = mm;
        }
    }
    __syncthreads();
    if (tid == 0) atomicAdd(accNonneg, redbuf[0] + redbuf[1] + redbuf[2] + redbuf[3]);
    if (tid < 128) {
        float mm = fmaxf(maxred[0][tid], maxred[1][tid]);
        int R = rowA0 + tid;
        if (R < M_) {
            int x = R / NA_, a = R - x * NA_;
            int y = yt / T_, t = yt - y * T_;
            maxvis[(((size_t)x * B_ + y) * NA_ + a) * T_ + t] = mm;
        }
    }
}

// ---------------- per-(x,y) aggregation over (a,t) ----------------
__global__ void aggregate_kernel(const float* __restrict__ maxvis,
                                 const float* __restrict__ thrPtr,
                                 const float* __restrict__ scalePtr,
                                 float* __restrict__ clipSims,
                                 float* __restrict__ accFrac,
                                 float* __restrict__ accSel)
{
    int xy = blockIdx.x;
    int x = xy / B_, y = xy % B_;
    int a = threadIdx.x;
    float th    = 1.0f / (1.0f + expf(-thrPtr[0]));
    float scale = scalePtr[0];
    float token = 0.0f, cnt = 0.0f, selsum = 0.0f;
    if (a < NA_) {
        const float* p = maxvis + (((size_t)x * B_ + y) * NA_ + a) * T_;
        float ws = 0.0f, ss = 0.0f;
        #pragma unroll
        for (int t = 0; t < T_; ++t) {
            float mv  = p[t];
            float rd  = mv - th;
            float sel = fmaxf(rd, 0.0f) * scale;
            ws += mv * sel;
            ss += sel;
            if (rd > 0.0f) cnt += 1.0f;
            if (x == y) selsum += 0.5f * (tanhf(20.0f * rd) + 1.0f);
        }
        token = ws / fmaxf(ss, 1e-6f);
    }
    #pragma unroll
    for (int off = 32; off; off >>= 1) {
        token  += __shfl_xor(token,  off, 64);
        cnt    += __shfl_xor(cnt,    off, 64);
        selsum += __shfl_xor(selsum, off, 64);
    }
    if (threadIdx.x == 0) {
        clipSims[x * B_ + y] = token / (float)NA_;
        atomicAdd(accFrac, cnt);
        if (x == y) atomicAdd(accSel, selsum);
    }
}

// ---------------- finalize ----------------
__global__ void finalize_kernel(const float* __restrict__ clipSims,
                                const float* __restrict__ accs,
                                const float* __restrict__ tempPtr,
                                const float* __restrict__ scalePtr,
                                const float* __restrict__ thrPtr,
                                float* __restrict__ out)
{
    __shared__ float cs[B_ * B_];
    int tid = threadIdx.x;  // 64
    for (int i = tid; i < B_ * B_; i += 64) cs[i] = clipSims[i];
    __syncthreads();
    float lsum = 0.0f;
    if (tid < B_) {
        int i = tid;
        float m = -1e30f;
        for (int j = 0; j < B_; ++j) m = fmaxf(m, cs[i * B_ + j]);
        float e = 0.0f;
        for (int j = 0; j < B_; ++j) e += expf(cs[i * B_ + j] - m);
        float la = m + logf(e) - cs[i * B_ + i];
        float m2 = -1e30f;
        for (int j = 0; j < B_; ++j) m2 = fmaxf(m2, cs[j * B_ + i]);
        float e2 = 0.0f;
        for (int j = 0; j < B_; ++j) e2 += expf(cs[j * B_ + i] - m2);
        float lv = m2 + logf(e2) - cs[i * B_ + i];
        lsum = la + lv;
    }
    #pragma unroll
    for (int off = 32; off; off >>= 1) lsum += __shfl_xor(lsum, off, 64);
    if (tid == 0) {
        float contrastive = lsum / (float)B_ * 0.5f;
        float temp = tempPtr[0], scl = scalePtr[0];
        float th = 1.0f / (1.0f + expf(-thrPtr[0]));
        float l_nonneg = accs[0] / 56448000.0f;   // B*B*NA*T*NV
        float logt = logf(temp);
        float tl  = fmaxf(-logt, 0.0f);
        float thi = fmaxf(logt - logf(4.0f), 0.0f);
        float l_cal = tl * tl + thi * thi;
        float t1 = fmaxf(th - 0.9f, 0.0f), t2 = fmaxf(0.1f - th, 0.0f);
        float l_thr = t1 * t1 + t2 * t2;
        float s1 = fmaxf(scl - 20.0f, 0.0f), s2 = fmaxf(1.0f - scl, 0.0f);
        float l_scale = s1 * s1 + s2 * s2;
        float reg = 0.15f * l_nonneg + 2.0f * l_cal + 0.1f * l_thr + 0.1f * l_scale;
        float frac   = accs[1] / 288000.0f;       // B*B*NA*T
        float selrew = -0.1f * log1pf(accs[2] / 12000.0f); // B*NA*T
        out[0] = selrew + contrastive + reg;
        out[1] = contrastive;
        out[2] = reg;
        out[3] = frac;
        out[4] = selrew;
    }
}

extern "C" void kernel_launch(void* const* d_in, const int* in_sizes, int n_in,
                              void* d_out, int out_size, void* d_ws, size_t ws_size,
                              hipStream_t stream) {
    const float* audio  = (const float*)d_in[0];  // (24,50,512)
    const float* visual = (const float*)d_in[1];  // (24,10,196,512)
    const float* temp   = (const float*)d_in[2];
    const float* scale  = (const float*)d_in[3];
    const float* thr    = (const float*)d_in[4];
    float* out = (float*)d_out;

    unsigned char* wsb = (unsigned char*)d_ws;
    unsigned short* Abf = (unsigned short*)wsb;                       // 1280*512*2    = 1,310,720 B
    unsigned short* Vbf = (unsigned short*)(wsb + 1310720);           // 53760*512*2   = 55,050,240 B
    float* maxvis   = (float*)(wsb + 1310720 + 55050240);             // 288000 floats = 1,152,000 B
    float* clipSims = (float*)(wsb + 1310720 + 55050240 + 1152000);   // 576 floats
    float* accs     = clipSims + 576;                                 // 3: [nonneg, frac, sel]

    normconv_kernel<<<(VROWS + MPAD) / 4, 256, 0, stream>>>(visual, audio, temp, Vbf, Abf, accs);

    dim3 grid(MPAD / 128, YT_);
    simred_kernel<<<grid, 256, 0, stream>>>(Abf, Vbf, maxvis, accs);

    aggregate_kernel<<<B_ * B_, 64, 0, stream>>>(maxvis, thr, scale, clipSims, accs + 1, accs + 2);
    finalize_kernel<<<1, 64, 0, stream>>>(clipSims, accs, temp, scale, thr, out);
}

// Round 4
// 307.601 us; speedup vs baseline: 1.2168x; 1.2168x over previous
//
#include <hip/hip_runtime.h>
#include <math.h>

#define B_   24
#define NA_  50
#define T_   10
#define NV_  196
#define D_   512
#define M_   1200          // B*NA audio rows
#define MPAD 1280          // padded to 10 tiles of 128
#define NVP  224           // 196 padded to 14*16
#define YT_  240           // B*T
#define VROWS (YT_ * NVP)  // 53760 padded visual rows
#define CHB  22528         // LDS staging bytes: A 8192 + V 14336

typedef __bf16 bf16x8 __attribute__((ext_vector_type(8)));
typedef float  f32x4  __attribute__((ext_vector_type(4)));
typedef unsigned short ushort8 __attribute__((ext_vector_type(8)));

__device__ __forceinline__ unsigned short f2bf(float f) {
    unsigned u = __float_as_uint(f);
    u += 0x7FFF + ((u >> 16) & 1);       // RNE
    return (unsigned short)(u >> 16);
}

__device__ __forceinline__ void gload16(const void* g, void* l) {
    __builtin_amdgcn_global_load_lds(
        (const __attribute__((address_space(1))) unsigned int*)g,
        (__attribute__((address_space(3))) unsigned int*)l, 16, 0, 0);
}

// ---- merged: L2-normalize + bf16 convert for V and A; also zero-inits accs ----
// grid: (VROWS + MPAD)/4 blocks x 256. One wave per row.
__global__ void normconv_kernel(const float* __restrict__ vf, const float* __restrict__ af,
                                const float* __restrict__ tempPtr,
                                unsigned short* __restrict__ Vbf, unsigned short* __restrict__ Abf,
                                float* __restrict__ accs) {
    if (blockIdx.x == 0 && threadIdx.x < 3) accs[threadIdx.x] = 0.0f;
    int w = threadIdx.x >> 6, lane = threadIdx.x & 63;
    int row = blockIdx.x * 4 + w;
    const float* p = nullptr;
    unsigned short* dstp;
    float tscale = 1.0f;
    if (row < VROWS) {
        int yt = row / NVP, vv = row - yt * NVP;
        dstp = Vbf + (size_t)row * D_;
        if (vv < NV_) p = vf + ((size_t)yt * NV_ + vv) * D_;
    } else {
        int ar = row - VROWS;
        if (ar >= MPAD) return;
        dstp = Abf + (size_t)ar * D_;
        if (ar < M_) { p = af + (size_t)ar * D_; tscale = tempPtr[0]; }
    }
    ushort8* dst = (ushort8*)(dstp + lane * 8);
    if (p) {
        float4 u = *(const float4*)(p + lane * 8);
        float4 v = *(const float4*)(p + lane * 8 + 4);
        float s = u.x*u.x + u.y*u.y + u.z*u.z + u.w*u.w
                + v.x*v.x + v.y*v.y + v.z*v.z + v.w*v.w;
        #pragma unroll
        for (int off = 32; off; off >>= 1) s += __shfl_xor(s, off, 64);
        float sc = 1.0f / (fmaxf(sqrtf(s), 1e-12f) * tscale);
        ushort8 o;
        o[0]=f2bf(u.x*sc); o[1]=f2bf(u.y*sc); o[2]=f2bf(u.z*sc); o[3]=f2bf(u.w*sc);
        o[4]=f2bf(v.x*sc); o[5]=f2bf(v.y*sc); o[6]=f2bf(v.z*sc); o[7]=f2bf(v.w*sc);
        *dst = o;
    } else {
        ushort8 z = (ushort8)0;
        *dst = z;
    }
}

// ---- MFMA GEMM + fused max/clip reductions, single-buffered, XCD-swizzled ----
// grid: (10, 240) remapped so each XCD owns 30 yt groups with row-tiles adjacent.
// block: 256 (4 waves, 2x2). Block tile: 128 rows x 224 cols, K=512, BK=32.
// LDS: 22 units of 1024B; unit u = 16 rows x 32 bf16 k-major:
//   elem(row r, k-chunk q of 8) at u*1024 + q*256 + r*16 -> conflict-free b128 frag reads.
__global__ __launch_bounds__(256) void simred_kernel(
    const unsigned short* __restrict__ Abf, const unsigned short* __restrict__ Vbf,
    float* __restrict__ maxvis, float* __restrict__ accNonneg)
{
    __shared__ __align__(16) unsigned char lds[CHB];
    __shared__ float maxred[2][128];
    __shared__ float redbuf[4];

    const int tid  = threadIdx.x;
    const int lane = tid & 63;
    const int w    = tid >> 6;
    const int q    = lane >> 4;    // k-piece (staging) / frag quad
    const int m16  = lane & 15;    // row (staging) / frag row index
    const int wr   = w & 1;        // wave row half (64 rows)
    const int wc   = w >> 1;       // wave col half (112 cols)

    // XCD-aware swizzle: flat%8 = XCD. Each XCD: 30 yts x 10 row-tiles (rt innermost).
    const int flat = blockIdx.x + gridDim.x * blockIdx.y;   // 0..2399
    const int xcd  = flat & 7;
    const int slot = flat >> 3;          // 0..299
    const int grp  = slot / 10;          // 0..29
    const int rt   = slot - grp * 10;    // 0..9
    const int yt   = xcd * 30 + grp;
    const int rowA0 = rt * 128;
    const size_t vRow0 = (size_t)yt * NVP;

    // staging units: 0..7 = A row blocks, 8..21 = V row blocks; lane -> (row m16, piece q)
    const unsigned short* gp[6];
    int lpOff[6];
    int nun = 0;
    #pragma unroll
    for (int i = 0; i < 6; ++i) {
        int u = w + 4 * i;
        if (u < 22) {
            if (u < 8) gp[nun] = Abf + (size_t)(rowA0 + u * 16 + m16) * D_ + q * 8;
            else       gp[nun] = Vbf + (vRow0 + (size_t)((u - 8) * 16 + m16)) * D_ + q * 8;
            lpOff[nun] = u * 1024;
            ++nun;
        }
    }

    // fragment offsets (k-major units)
    int aOff[4], bOff[7];
    #pragma unroll
    for (int i = 0; i < 4; ++i) aOff[i] = (wr * 4 + i) * 1024 + q * 256 + m16 * 16;
    #pragma unroll
    for (int j = 0; j < 7; ++j) bOff[j] = 8192 + (wc * 7 + j) * 1024 + q * 256 + m16 * 16;

    f32x4 acc[4][7];
    #pragma unroll
    for (int i = 0; i < 4; ++i)
        #pragma unroll
        for (int j = 0; j < 7; ++j) acc[i][j] = (f32x4)0.0f;

    for (int c = 0; c < 16; ++c) {
        __syncthreads();                       // prev chunk's frag reads done
        #pragma unroll
        for (int i = 0; i < 6; ++i)
            if (i < nun) gload16(gp[i] + c * 32, lds + lpOff[i]);
        __syncthreads();                       // staging drained
        bf16x8 afr[4], bfr[7];
        #pragma unroll
        for (int i = 0; i < 4; ++i) afr[i] = *(const bf16x8*)(lds + aOff[i]);
        #pragma unroll
        for (int j = 0; j < 7; ++j) bfr[j] = *(const bf16x8*)(lds + bOff[j]);
        #pragma unroll
        for (int i = 0; i < 4; ++i)
            #pragma unroll
            for (int j = 0; j < 7; ++j)
                acc[i][j] = __builtin_amdgcn_mfma_f32_16x16x32_bf16(afr[i], bfr[j], acc[i][j], 0, 0, 0);
    }

    // ---- clip(s,-20,0)^2 partial sum (zero-padded rows/cols contribute exactly 0) ----
    float cs = 0.0f;
    #pragma unroll
    for (int i = 0; i < 4; ++i)
        #pragma unroll
        for (int j = 0; j < 7; ++j)
            #pragma unroll
            for (int r = 0; r < 4; ++r) {
                float v = acc[i][j][r];
                float cv = fminf(fmaxf(v, -20.0f), 0.0f);
                cs += cv * cv;
            }
    #pragma unroll
    for (int off = 32; off; off >>= 1) cs += __shfl_xor(cs, off, 64);
    if (lane == 0) redbuf[w] = cs;

    // ---- per-row max over valid cols (C/D: col=lane&15, row=q*4+reg) ----
    bool colv[7];
    #pragma unroll
    for (int j = 0; j < 7; ++j) colv[j] = (wc * 112 + j * 16 + m16) < NV_;
    #pragma unroll
    for (int i = 0; i < 4; ++i) {
        float mx[4] = {-3e38f, -3e38f, -3e38f, -3e38f};
        #pragma unroll
        for (int j = 0; j < 7; ++j)
            #pragma unroll
            for (int r = 0; r < 4; ++r)
                mx[r] = fmaxf(mx[r], colv[j] ? acc[i][j][r] : -3e38f);
        #pragma unroll
        for (int r = 0; r < 4; ++r) {
            float mm = mx[r];
            #pragma unroll
            for (int off = 1; off <= 8; off <<= 1) mm = fmaxf(mm, __shfl_xor(mm, off, 64));
            if (m16 == 0) maxred[wc][wr * 64 + i * 16 + q * 4 + r] = mm;
        }
    }
    __syncthreads();
    if (tid == 0) atomicAdd(accNonneg, redbuf[0] + redbuf[1] + redbuf[2] + redbuf[3]);
    if (tid < 128) {
        float mm = fmaxf(maxred[0][tid], maxred[1][tid]);
        int R = rowA0 + tid;
        if (R < M_) {
            int x = R / NA_, a = R - x * NA_;
            int y = yt / T_, t = yt - y * T_;
            maxvis[(((size_t)x * B_ + y) * NA_ + a) * T_ + t] = mm;
        }
    }
}

// ---------------- per-(x,y) aggregation over (a,t) ----------------
__global__ void aggregate_kernel(const float* __restrict__ maxvis,
                                 const float* __restrict__ thrPtr,
                                 const float* __restrict__ scalePtr,
                                 float* __restrict__ clipSims,
                                 float* __restrict__ accFrac,
                                 float* __restrict__ accSel)
{
    int xy = blockIdx.x;
    int x = xy / B_, y = xy % B_;
    int a = threadIdx.x;
    float th    = 1.0f / (1.0f + expf(-thrPtr[0]));
    float scale = scalePtr[0];
    float token = 0.0f, cnt = 0.0f, selsum = 0.0f;
    if (a < NA_) {
        const float* p = maxvis + (((size_t)x * B_ + y) * NA_ + a) * T_;
        float ws = 0.0f, ss = 0.0f;
        #pragma unroll
        for (int t = 0; t < T_; ++t) {
            float mv  = p[t];
            float rd  = mv - th;
            float sel = fmaxf(rd, 0.0f) * scale;
            ws += mv * sel;
            ss += sel;
            if (rd > 0.0f) cnt += 1.0f;
            if (x == y) selsum += 0.5f * (tanhf(20.0f * rd) + 1.0f);
        }
        token = ws / fmaxf(ss, 1e-6f);
    }
    #pragma unroll
    for (int off = 32; off; off >>= 1) {
        token  += __shfl_xor(token,  off, 64);
        cnt    += __shfl_xor(cnt,    off, 64);
        selsum += __shfl_xor(selsum, off, 64);
    }
    if (threadIdx.x == 0) {
        clipSims[x * B_ + y] = token / (float)NA_;
        atomicAdd(accFrac, cnt);
        if (x == y) atomicAdd(accSel, selsum);
    }
}

// ---------------- finalize ----------------
__global__ void finalize_kernel(const float* __restrict__ clipSims,
                                const float* __restrict__ accs,
                                const float* __restrict__ tempPtr,
                                const float* __restrict__ scalePtr,
                                const float* __restrict__ thrPtr,
                                float* __restrict__ out)
{
    __shared__ float cs[B_ * B_];
    int tid = threadIdx.x;  // 64
    for (int i = tid; i < B_ * B_; i += 64) cs[i] = clipSims[i];
    __syncthreads();
    float lsum = 0.0f;
    if (tid < B_) {
        int i = tid;
        float m = -1e30f;
        for (int j = 0; j < B_; ++j) m = fmaxf(m, cs[i * B_ + j]);
        float e = 0.0f;
        for (int j = 0; j < B_; ++j) e += expf(cs[i * B_ + j] - m);
        float la = m + logf(e) - cs[i * B_ + i];
        float m2 = -1e30f;
        for (int j = 0; j < B_; ++j) m2 = fmaxf(m2, cs[j * B_ + i]);
        float e2 = 0.0f;
        for (int j = 0; j < B_; ++j) e2 += expf(cs[j * B_ + i] - m2);
        float lv = m2 + logf(e2) - cs[i * B_ + i];
        lsum = la + lv;
    }
    #pragma unroll
    for (int off = 32; off; off >>= 1) lsum += __shfl_xor(lsum, off, 64);
    if (tid == 0) {
        float contrastive = lsum / (float)B_ * 0.5f;
        float temp = tempPtr[0], scl = scalePtr[0];
        float th = 1.0f / (1.0f + expf(-thrPtr[0]));
        float l_nonneg = accs[0] / 56448000.0f;   // B*B*NA*T*NV
        float logt = logf(temp);
        float tl  = fmaxf(-logt, 0.0f);
        float thi = fmaxf(logt - logf(4.0f), 0.0f);
        float l_cal = tl * tl + thi * thi;
        float t1 = fmaxf(th - 0.9f, 0.0f), t2 = fmaxf(0.1f - th, 0.0f);
        float l_thr = t1 * t1 + t2 * t2;
        float s1 = fmaxf(scl - 20.0f, 0.0f), s2 = fmaxf(1.0f - scl, 0.0f);
        float l_scale = s1 * s1 + s2 * s2;
        float reg = 0.15f * l_nonneg + 2.0f * l_cal + 0.1f * l_thr + 0.1f * l_scale;
        float frac   = accs[1] / 288000.0f;       // B*B*NA*T
        float selrew = -0.1f * log1pf(accs[2] / 12000.0f); // B*NA*T
        out[0] = selrew + contrastive + reg;
        out[1] = contrastive;
        out[2] = reg;
        out[3] = frac;
        out[4] = selrew;
    }
}

extern "C" void kernel_launch(void* const* d_in, const int* in_sizes, int n_in,
                              void* d_out, int out_size, void* d_ws, size_t ws_size,
                              hipStream_t stream) {
    const float* audio  = (const float*)d_in[0];  // (24,50,512)
    const float* visual = (const float*)d_in[1];  // (24,10,196,512)
    const float* temp   = (const float*)d_in[2];
    const float* scale  = (const float*)d_in[3];
    const float* thr    = (const float*)d_in[4];
    float* out = (float*)d_out;

    unsigned char* wsb = (unsigned char*)d_ws;
    unsigned short* Abf = (unsigned short*)wsb;                       // 1280*512*2    = 1,310,720 B
    unsigned short* Vbf = (unsigned short*)(wsb + 1310720);           // 53760*512*2   = 55,050,240 B
    float* maxvis   = (float*)(wsb + 1310720 + 55050240);             // 288000 floats = 1,152,000 B
    float* clipSims = (float*)(wsb + 1310720 + 55050240 + 1152000);   // 576 floats
    float* accs     = clipSims + 576;                                 // 3: [nonneg, frac, sel]

    normconv_kernel<<<(VROWS + MPAD) / 4, 256, 0, stream>>>(visual, audio, temp, Vbf, Abf, accs);

    dim3 grid(MPAD / 128, YT_);
    simred_kernel<<<grid, 256, 0, stream>>>(Abf, Vbf, maxvis, accs);

    aggregate_kernel<<<B_ * B_, 64, 0, stream>>>(maxvis, thr, scale, clipSims, accs + 1, accs + 2);
    finalize_kernel<<<1, 64, 0, stream>>>(clipSims, accs, temp, scale, thr, out);
}